// Round 4
// baseline (5692.010 us; speedup 1.0000x reference)
//
#include <hip/hip_runtime.h>
#include <cstdint>
#include <cstddef>

// ---------------------------------------------------------------------------
// ViT forward, MI355X. B=512, DIM=384, HEADS=6, DH=64, DEPTH=12, MLP=1536,
// N=65 tokens, top-K=16 sparse attention with relative position bias.
// bf16 MFMA (16x16x32) for all GEMMs, fp32 residual/LN/softmax/PV weights.
// R4: attention split into k_attnA (QK^T+bias -> fp32 scores^T in global,
//     L3-resident) and k_attnB (topk scan with conflict-free column reads,
//     rows spread across both waves; PV from bank-padded LDS V).
// ---------------------------------------------------------------------------

typedef __attribute__((ext_vector_type(8))) short bf16x8;
typedef __attribute__((ext_vector_type(4))) float f32x4;
typedef __attribute__((ext_vector_type(4))) unsigned short u16x4;

__device__ __forceinline__ unsigned short f2bf(float f) {
  unsigned u = __float_as_uint(f);
  u += 0x7FFF + ((u >> 16) & 1);            // RNE
  return (unsigned short)(u >> 16);
}
__device__ __forceinline__ float bf2f(unsigned short h) {
  return __uint_as_float(((unsigned)h) << 16);
}
__device__ __forceinline__ float gelu_f(float v) {
  return 0.5f * v * (1.f + erff(v * 0.70710678118654752440f));
}

typedef const __attribute__((address_space(1))) unsigned int* gas1_t;
typedef __attribute__((address_space(3))) unsigned int* las3_t;
__device__ __forceinline__ void async16(const void* g, void* l) {
  __builtin_amdgcn_global_load_lds((gas1_t)g, (las3_t)l, 16, 0, 0);
}

// ---------------------------------------------------------------------------
// Weight convert: fp32 [mat][K][N] -> bf16 [mat][Npad][K] (transposed, padded)
// ---------------------------------------------------------------------------
__global__ void k_tconv(const float* __restrict__ in, unsigned short* __restrict__ out,
                        int K, int N, int Npad, int total) {
  int idx = blockIdx.x * 256 + threadIdx.x;
  if (idx >= total) return;
  int per = Npad * K;
  int mat = idx / per;
  int rem = idx - mat * per;
  int n = rem / K;
  int kk = rem - n * K;
  float v = 0.f;
  if (n < N) v = in[(size_t)mat * K * N + (size_t)kk * N + n];
  out[idx] = f2bf(v);
}

__global__ void k_padhb(const float* __restrict__ hb, float* __restrict__ out) {
  int i = blockIdx.x * 256 + threadIdx.x;
  if (i < 1024) out[i] = (i < 1000) ? hb[i] : 0.f;
}

// ---------------------------------------------------------------------------
// Patch extraction + LN over 768 -> bf16 rows [32768 x 768]
// ---------------------------------------------------------------------------
__global__ void k_patchln(const float* __restrict__ img,
                          const float* __restrict__ w1, const float* __restrict__ b1,
                          unsigned short* __restrict__ Xp) {
  const int p = blockIdx.x;               // b*64 + patch
  const int b = p >> 6, pl = p & 63;
  const int gr = pl >> 3, gc = pl & 7;
  const int t = threadIdx.x;              // 256
  __shared__ float buf[768];
  __shared__ float ps[4], ps2[4];
#pragma unroll
  for (int s = 0; s < 3; ++s) {
    int rr = s * 16 + (t >> 4);           // 0..47 = (c,p1)
    int c = rr >> 4, p1 = rr & 15, p2 = t & 15;
    float v = img[(((size_t)b * 3 + c) * 128 + (gr * 16 + p1)) * 128 + gc * 16 + p2];
    buf[(p1 * 16 + p2) * 3 + c] = v;
  }
  __syncthreads();
  float e0 = buf[t], e1 = buf[t + 256], e2 = buf[t + 512];
  float s = e0 + e1 + e2;
  float s2 = e0 * e0 + e1 * e1 + e2 * e2;
  for (int off = 32; off; off >>= 1) { s += __shfl_xor(s, off); s2 += __shfl_xor(s2, off); }
  if ((t & 63) == 0) { ps[t >> 6] = s; ps2[t >> 6] = s2; }
  __syncthreads();
  float S = ps[0] + ps[1] + ps[2] + ps[3];
  float S2 = ps2[0] + ps2[1] + ps2[2] + ps2[3];
  float mu = S * (1.f / 768.f);
  float rs = rsqrtf(S2 * (1.f / 768.f) - mu * mu + 1e-5f);
  size_t ob = (size_t)p * 768;
  Xp[ob + t]       = f2bf((e0 - mu) * rs * w1[t]       + b1[t]);
  Xp[ob + t + 256] = f2bf((e1 - mu) * rs * w1[t + 256] + b1[t + 256]);
  Xp[ob + t + 512] = f2bf((e2 - mu) * rs * w1[t + 512] + b1[t + 512]);
}

// ---------------------------------------------------------------------------
// LN over 384 (fp32 in) -> bf16 out. 128 threads/row.
// ---------------------------------------------------------------------------
__global__ void k_ln384(const float* __restrict__ X, const float* __restrict__ w,
                        const float* __restrict__ bb, unsigned short* __restrict__ H) {
  const int row = blockIdx.x;
  const int t = threadIdx.x;
  const float* xr = X + (size_t)row * 384;
  float e0 = xr[t], e1 = xr[t + 128], e2 = xr[t + 256];
  float s = e0 + e1 + e2, s2 = e0 * e0 + e1 * e1 + e2 * e2;
  for (int off = 32; off; off >>= 1) { s += __shfl_xor(s, off); s2 += __shfl_xor(s2, off); }
  __shared__ float ps[2], ps2[2];
  if ((t & 63) == 0) { ps[t >> 6] = s; ps2[t >> 6] = s2; }
  __syncthreads();
  float S = ps[0] + ps[1], S2 = ps2[0] + ps2[1];
  float mu = S * (1.f / 384.f);
  float rs = rsqrtf(S2 * (1.f / 384.f) - mu * mu + 1e-5f);
  size_t ob = (size_t)row * 384;
  H[ob + t]       = f2bf((e0 - mu) * rs * w[t]       + bb[t]);
  H[ob + t + 128] = f2bf((e1 - mu) * rs * w[t + 128] + bb[t + 128]);
  H[ob + t + 256] = f2bf((e2 - mu) * rs * w[t + 256] + bb[t + 256]);
}

// LN(cls row) -> bf16 [512 x 384]
__global__ void k_lncls(const float* __restrict__ X, const float* __restrict__ w,
                        const float* __restrict__ bb, unsigned short* __restrict__ H) {
  const int b = blockIdx.x;
  const int t = threadIdx.x;
  const float* xr = X + (size_t)b * 65 * 384;
  float e0 = xr[t], e1 = xr[t + 128], e2 = xr[t + 256];
  float s = e0 + e1 + e2, s2 = e0 * e0 + e1 * e1 + e2 * e2;
  for (int off = 32; off; off >>= 1) { s += __shfl_xor(s, off); s2 += __shfl_xor(s2, off); }
  __shared__ float ps[2], ps2[2];
  if ((t & 63) == 0) { ps[t >> 6] = s; ps2[t >> 6] = s2; }
  __syncthreads();
  float S = ps[0] + ps[1], S2 = ps2[0] + ps2[1];
  float mu = S * (1.f / 384.f);
  float rs = rsqrtf(S2 * (1.f / 384.f) - mu * mu + 1e-5f);
  size_t ob = (size_t)b * 384;
  H[ob + t]       = f2bf((e0 - mu) * rs * w[t]       + bb[t]);
  H[ob + t + 128] = f2bf((e1 - mu) * rs * w[t + 128] + bb[t + 128]);
  H[ob + t + 256] = f2bf((e2 - mu) * rs * w[t + 256] + bb[t + 256]);
}

// LN(patch-embed GEMM out) + pos_emb -> x fp32 rows (token 1+pl)
__global__ void k_ln2pos(const float* __restrict__ tmp, const float* __restrict__ w,
                         const float* __restrict__ bb, const float* __restrict__ pos,
                         float* __restrict__ Xout) {
  const int p = blockIdx.x;               // 0..32767
  const int b = p >> 6, pl = p & 63;
  const int t = threadIdx.x;
  const float* xr = tmp + (size_t)p * 384;
  float e0 = xr[t], e1 = xr[t + 128], e2 = xr[t + 256];
  float s = e0 + e1 + e2, s2 = e0 * e0 + e1 * e1 + e2 * e2;
  for (int off = 32; off; off >>= 1) { s += __shfl_xor(s, off); s2 += __shfl_xor(s2, off); }
  __shared__ float ps[2], ps2[2];
  if ((t & 63) == 0) { ps[t >> 6] = s; ps2[t >> 6] = s2; }
  __syncthreads();
  float S = ps[0] + ps[1], S2 = ps2[0] + ps2[1];
  float mu = S * (1.f / 384.f);
  float rs = rsqrtf(S2 * (1.f / 384.f) - mu * mu + 1e-5f);
  const float* pr = pos + (size_t)(1 + pl) * 384;
  float* orow = Xout + ((size_t)b * 65 + 1 + pl) * 384;
  orow[t]       = (e0 - mu) * rs * w[t]       + bb[t]       + pr[t];
  orow[t + 128] = (e1 - mu) * rs * w[t + 128] + bb[t + 128] + pr[t + 128];
  orow[t + 256] = (e2 - mu) * rs * w[t + 256] + bb[t + 256] + pr[t + 256];
}

__global__ void k_cls(const float* __restrict__ cls, const float* __restrict__ pos,
                      float* __restrict__ Xout) {
  int idx = blockIdx.x * 256 + threadIdx.x;
  if (idx >= 512 * 384) return;
  int b = idx / 384, d = idx - b * 384;
  Xout[(size_t)b * 65 * 384 + d] = cls[d] + pos[d];
}

// ---------------------------------------------------------------------------
// GEMM: C[M x Nreal] = A_bf16[M x K] @ Wt_bf16[Npad x K]^T (+bias)(+gelu)(+res)
// 128x128 tile, BK=64, 256 thr = 4 waves (2x2 of 64x64), mfma 16x16x32 bf16.
// EPI: 0=none 1=bias 2=bias+gelu 3=bias+residual.  OUTBF: 1 -> bf16 out.
// ---------------------------------------------------------------------------
template <int EPI, int OUTBF>
__global__ __launch_bounds__(256, 2) void k_gemm(
    const unsigned short* __restrict__ A,
    const unsigned short* __restrict__ Wt,
    const float* __restrict__ bias,
    const float* __restrict__ Res,
    void* __restrict__ Out,
    int K, int Nreal) {
  __shared__ alignas(16) unsigned short As[128 * 64];
  __shared__ alignas(16) unsigned short Bs[128 * 64];
  const int t = threadIdx.x;
  const int w = t >> 6, l = t & 63;
  const int m0 = blockIdx.x * 128, n0 = blockIdx.y * 128;
  const int wm = w & 1, wn = w >> 1;

  f32x4 acc[4][4] = {};

  const int rA = t >> 3;                   // 0..31
  const int cb = t & 7;                    // 16B chunk in row
  const unsigned short* Ag = A + (size_t)(m0 + rA) * K + cb * 8;
  const unsigned short* Bg = Wt + (size_t)(n0 + rA) * K + cb * 8;

  for (int k0 = 0; k0 < K; k0 += 64) {
#pragma unroll
    for (int p = 0; p < 4; ++p) {
      async16(Ag + (size_t)(p * 32) * K + k0, &As[p * 2048 + t * 8]);
      async16(Bg + (size_t)(p * 32) * K + k0, &Bs[p * 2048 + t * 8]);
    }
    __syncthreads();
#pragma unroll
    for (int kk = 0; kk < 64; kk += 32) {
      bf16x8 af[4], bfr[4];
      const int kof = kk + (l >> 4) * 8;
      const int rsel = l & 15;
#pragma unroll
      for (int i = 0; i < 4; ++i) {
        af[i]  = *(const bf16x8*)&As[(wm * 64 + i * 16 + rsel) * 64 + kof];
        bfr[i] = *(const bf16x8*)&Bs[(wn * 64 + i * 16 + rsel) * 64 + kof];
      }
#pragma unroll
      for (int i = 0; i < 4; ++i)
#pragma unroll
        for (int j = 0; j < 4; ++j)
          acc[i][j] = __builtin_amdgcn_mfma_f32_16x16x32_bf16(af[i], bfr[j], acc[i][j], 0, 0, 0);
    }
    __syncthreads();
  }

  const int colq = l & 15, rowq = (l >> 4) * 4;
#pragma unroll
  for (int i = 0; i < 4; ++i) {
    const int rb = m0 + wm * 64 + i * 16 + rowq;
#pragma unroll
    for (int j = 0; j < 4; ++j) {
      const int c = n0 + wn * 64 + j * 16 + colq;
      float bv = 0.f;
      if (EPI >= 1) bv = bias[c];
#pragma unroll
      for (int rg = 0; rg < 4; ++rg) {
        const int r = rb + rg;
        float v = acc[i][j][rg] + bv;
        if (EPI == 2) v = gelu_f(v);
        if (EPI == 3) v += Res[(size_t)r * Nreal + c];
        if (c < Nreal) {
          if (OUTBF) ((unsigned short*)Out)[(size_t)r * Nreal + c] = f2bf(v);
          else       ((float*)Out)[(size_t)r * Nreal + c] = v;
        }
      }
    }
  }
}

// ---------------------------------------------------------------------------
// k_attnA: per (b,h): scores^T[j][i] = dot(q_i,k_j)*0.125 + relpos bias,
// written fp32 to global [blk][65][68] (L3-resident). MFMA operands swapped
// (K first) so D rows = key index -> conflict-free LDS writes + coalesced out.
// ---------------------------------------------------------------------------
__global__ __launch_bounds__(256, 4) void k_attnA(
    const unsigned short* __restrict__ qkvb,
    const float* __restrict__ btab,
    float* __restrict__ scores) {
  const int blk = blockIdx.x;
  const int b = blk / 6, h = blk - b * 6;
  __shared__ alignas(16) union UU {
    unsigned short qk[2 * 80 * 64];       // 20480 B: q rows [80x64], k rows [80x64]
    float ds[65 * 68];                    // 17680 B, overlaid after mfma phase
  } u;
  __shared__ float btl[225];
  const int t = threadIdx.x;
  const size_t base = (size_t)b * 65 * 1152 + h * 64;

  if (t < 225) btl[t] = btab[t];
  for (int idx = t; idx < 520; idx += 256) {
    int r = idx >> 3, c = idx & 7;
    const unsigned short* gp = qkvb + base + (size_t)r * 1152 + c * 8;
    async16(gp, &u.qk[idx * 8]);
    async16(gp + 384, &u.qk[80 * 64 + idx * 8]);
  }
  __syncthreads();

  const int w = t >> 6, l = t & 63;
  f32x4 accs[7];
#pragma unroll
  for (int s = 0; s < 7; ++s) {
    int tt = w + s * 4;
    f32x4 a = {0.f, 0.f, 0.f, 0.f};
    if (tt < 25) {
      int ti = tt / 5, tq = tt - ti * 5;  // ti: key tile (D rows), tq: query tile (D cols)
#pragma unroll
      for (int kk = 0; kk < 64; kk += 32) {
        int kof = kk + (l >> 4) * 8;
        bf16x8 kb = *(const bf16x8*)&u.qk[80 * 64 + (ti * 16 + (l & 15)) * 64 + kof];
        bf16x8 qa = *(const bf16x8*)&u.qk[(tq * 16 + (l & 15)) * 64 + kof];
        a = __builtin_amdgcn_mfma_f32_16x16x32_bf16(kb, qa, a, 0, 0, 0);
      }
    }
    accs[s] = a;
  }
  __syncthreads();                         // all qk reads done; overlay ds

#pragma unroll
  for (int s = 0; s < 7; ++s) {
    int tt = w + s * 4;
    if (tt < 25) {
      int ti = tt / 5, tq = tt - ti * 5;
      int i = tq * 16 + (l & 15);          // query (col)
      int jb = ti * 16 + (l >> 4) * 4;     // key base (row)
      if (i < 65) {
#pragma unroll
        for (int rg = 0; rg < 4; ++rg) {
          int j = jb + rg;
          if (j < 65) {
            float bias = 0.f;
            if (i > 0 && j > 0) {
              int ri = (i - 1) >> 3, ci = (i - 1) & 7;
              int rj = (j - 1) >> 3, cj = (j - 1) & 7;
              bias = btl[(ri - rj + 7) * 15 + (ci - cj + 7)];
            }
            u.ds[j * 68 + i] = accs[s][rg] * 0.125f + bias;
          }
        }
      }
    }
  }
  __syncthreads();

  float* sg = scores + (size_t)blk * 4420;
  for (int idx = t; idx < 1105; idx += 256)
    *(f32x4*)(sg + idx * 4) = *(const f32x4*)&u.ds[idx * 4];
}

// ---------------------------------------------------------------------------
// k_attnB: per (b,h): top-16/row from scores^T (conflict-free column reads,
// rows even/odd across the 2 waves), softmax weights, PV from LDS V.
// Selection: strict-greater pass then tie pass in index order == jax top_k.
// ---------------------------------------------------------------------------
__global__ __launch_bounds__(128, 2) void k_attnB(
    const unsigned short* __restrict__ qkvb,
    const float* __restrict__ scores,
    unsigned short* __restrict__ Obuf) {
  const int blk = blockIdx.x;
  const int b = blk / 6, h = blk - b * 6;
  __shared__ alignas(16) float scl[65 * 68];            // 17680 B
  __shared__ alignas(16) unsigned short vsb[65 * 72];   // 9360 B (pad 72)
  __shared__ float wsel[65 * 16];
  __shared__ short seli[65 * 16];
  const int t = threadIdx.x;
  const size_t base = (size_t)b * 65 * 1152 + h * 64;
  const float* sg = scores + (size_t)blk * 4420;

  for (int idx = t; idx < 1105; idx += 128)
    async16(sg + idx * 4, &scl[idx * 4]);
  for (int idx = t; idx < 520; idx += 128) {
    int r = idx >> 3, c = idx & 7;
    bf16x8 raw = *(const bf16x8*)(qkvb + base + (size_t)r * 1152 + 768 + c * 8);
    *(bf16x8*)&vsb[r * 72 + c * 8] = raw;
  }
  __syncthreads();

  const int wv = t >> 6, l = t & 63;
  const int r = 2 * l + wv;                // wave0: even rows, wave1: odd rows
  const bool act = wv ? (l < 32) : (l <= 32);
  if (act) {
    float lv[16];
#pragma unroll
    for (int i = 0; i < 16; ++i) lv[i] = -3.4e38f;
    for (int j = 0; j < 65; ++j) {
      float x = scl[j * 68 + r];
#pragma unroll
      for (int i = 0; i < 16; ++i) {
        float lo = fminf(lv[i], x);
        lv[i] = fmaxf(lv[i], x);
        x = lo;
      }
    }
    float m0 = lv[0];
    float sum = 0.f;
#pragma unroll
    for (int i = 0; i < 16; ++i) sum += __expf(lv[i] - m0);
    float inv = 1.f / sum;
    float vt = lv[15];
    int pos = 0;
    for (int j = 0; j < 65; ++j) {         // strictly-greater pass
      float v = scl[j * 68 + r];
      if (v > vt && pos < 16) {
        wsel[r * 16 + pos] = __expf(v - m0) * inv;
        seli[r * 16 + pos] = (short)j;
        ++pos;
      }
    }
    for (int j = 0; j < 65; ++j) {         // tie pass, index order
      float v = scl[j * 68 + r];
      if (v == vt && pos < 16) {
        wsel[r * 16 + pos] = __expf(v - m0) * inv;
        seli[r * 16 + pos] = (short)j;
        ++pos;
      }
    }
  }
  __syncthreads();

  const size_t obase = (size_t)b * 65 * 384 + h * 64;
  for (int task = t; task < 65 * 16; task += 128) {
    int i = task >> 4, dc = task & 15;
    float a0 = 0.f, a1 = 0.f, a2 = 0.f, a3 = 0.f;
#pragma unroll
    for (int s = 0; s < 16; ++s) {
      float wv2 = wsel[i * 16 + s];
      int j = seli[i * 16 + s];
      u16x4 raw = *(const u16x4*)&vsb[j * 72 + dc * 4];
      a0 += wv2 * bf2f(raw.x);
      a1 += wv2 * bf2f(raw.y);
      a2 += wv2 * bf2f(raw.z);
      a3 += wv2 * bf2f(raw.w);
    }
    u16x4 o = {f2bf(a0), f2bf(a1), f2bf(a2), f2bf(a3)};
    *(u16x4*)&Obuf[obase + (size_t)i * 384 + dc * 4] = o;
  }
}

// ---------------------------------------------------------------------------
extern "C" void kernel_launch(void* const* d_in, const int* in_sizes, int n_in,
                              void* d_out, int out_size, void* d_ws, size_t ws_size,
                              hipStream_t stream) {
  (void)in_sizes; (void)n_in; (void)out_size; (void)ws_size;
  const float* img       = (const float*)d_in[0];
  const float* pe_ln1_w  = (const float*)d_in[1];
  const float* pe_ln1_b  = (const float*)d_in[2];
  const float* pe_w      = (const float*)d_in[3];
  const float* pe_b      = (const float*)d_in[4];
  const float* pe_ln2_w  = (const float*)d_in[5];
  const float* pe_ln2_b  = (const float*)d_in[6];
  const float* cls_tok   = (const float*)d_in[7];
  const float* pos_emb   = (const float*)d_in[8];
  const float* attn_ln_w = (const float*)d_in[9];
  const float* attn_ln_b = (const float*)d_in[10];
  const float* qkv_w     = (const float*)d_in[11];
  const float* out_w     = (const float*)d_in[12];
  const float* out_b     = (const float*)d_in[13];
  const float* btab      = (const float*)d_in[14];
  const float* ff_ln_w   = (const float*)d_in[15];
  const float* ff_ln_b   = (const float*)d_in[16];
  const float* ff_w1     = (const float*)d_in[17];
  const float* ff_b1     = (const float*)d_in[18];
  const float* ff_w2     = (const float*)d_in[19];
  const float* ff_b2     = (const float*)d_in[20];
  const float* fin_ln_w  = (const float*)d_in[21];
  const float* fin_ln_b  = (const float*)d_in[22];
  const float* head_w    = (const float*)d_in[23];
  const float* head_b    = (const float*)d_in[24];

  char* ws = (char*)d_ws;
  unsigned short* wt_pe   = (unsigned short*)(ws + 0);          //  384 x 768
  unsigned short* wt_qkv  = (unsigned short*)(ws + 589824);     // 12 x 1152 x 384
  unsigned short* wt_out  = (unsigned short*)(ws + 11206656);   // 12 x 384 x 384
  unsigned short* wt_ff1  = (unsigned short*)(ws + 14745600);   // 12 x 1536 x 384
  unsigned short* wt_ff2  = (unsigned short*)(ws + 28901376);   // 12 x 384 x 1536
  unsigned short* wt_head = (unsigned short*)(ws + 43057152);   // 1024 x 384
  float*          hb_pad  = (float*)(ws + 43843584);            // 1024
  float*          x       = (float*)(ws + 43847680);            // 33280 x 384 f32
  unsigned short* hbuf    = (unsigned short*)(ws + 94965760);   // 33280 x 384 bf16 (h / o)
  unsigned short* qkvb    = (unsigned short*)(ws + 120524800);  // 33280 x 1152 bf16
  unsigned short* h1      = (unsigned short*)(ws + 197201920);  // 33280 x 1536 bf16
  unsigned short* xcls    = (unsigned short*)(ws + 299438080);  // 512 x 384 bf16

  unsigned short* Xp = qkvb;          // overlay: 32768x768 bf16, pre-layer only
  float* tmp = (float*)h1;            // overlay: 32768x384 f32, pre-layer only
  float* scoresb = (float*)h1;        // overlay: 3072 x 4420 f32 (54 MB), attn phase only

  // one-time (per launch) weight transpose + bf16 convert
  k_tconv<<<dim3((294912 + 255) / 256), 256, 0, stream>>>(pe_w, wt_pe, 768, 384, 384, 294912);
  k_tconv<<<dim3((5308416 + 255) / 256), 256, 0, stream>>>(qkv_w, wt_qkv, 384, 1152, 1152, 5308416);
  k_tconv<<<dim3((1769472 + 255) / 256), 256, 0, stream>>>(out_w, wt_out, 384, 384, 384, 1769472);
  k_tconv<<<dim3((7077888 + 255) / 256), 256, 0, stream>>>(ff_w1, wt_ff1, 384, 1536, 1536, 7077888);
  k_tconv<<<dim3((7077888 + 255) / 256), 256, 0, stream>>>(ff_w2, wt_ff2, 1536, 384, 384, 7077888);
  k_tconv<<<dim3((393216 + 255) / 256), 256, 0, stream>>>(head_w, wt_head, 384, 1000, 1024, 393216);
  k_padhb<<<4, 256, 0, stream>>>(head_b, hb_pad);

  // patch embed
  k_patchln<<<32768, 256, 0, stream>>>(img, pe_ln1_w, pe_ln1_b, Xp);
  k_gemm<1, 0><<<dim3(256, 3), 256, 0, stream>>>(Xp, wt_pe, pe_b, nullptr, tmp, 768, 384);
  k_ln2pos<<<32768, 128, 0, stream>>>(tmp, pe_ln2_w, pe_ln2_b, pos_emb, x);
  k_cls<<<768, 256, 0, stream>>>(cls_tok, pos_emb, x);

  for (int lay = 0; lay < 12; ++lay) {
    k_ln384<<<33280, 128, 0, stream>>>(x, attn_ln_w + lay * 384, attn_ln_b + lay * 384, hbuf);
    k_gemm<0, 1><<<dim3(260, 9), 256, 0, stream>>>(hbuf, wt_qkv + (size_t)lay * 442368,
                                                   nullptr, nullptr, qkvb, 384, 1152);
    k_attnA<<<3072, 256, 0, stream>>>(qkvb, btab + lay * 225, scoresb);
    k_attnB<<<3072, 128, 0, stream>>>(qkvb, scoresb, hbuf);
    k_gemm<3, 0><<<dim3(260, 3), 256, 0, stream>>>(hbuf, wt_out + (size_t)lay * 147456,
                                                   out_b + lay * 384, x, x, 384, 384);
    k_ln384<<<33280, 128, 0, stream>>>(x, ff_ln_w + lay * 384, ff_ln_b + lay * 384, hbuf);
    k_gemm<2, 1><<<dim3(260, 12), 256, 0, stream>>>(hbuf, wt_ff1 + (size_t)lay * 589824,
                                                    ff_b1 + lay * 1536, nullptr, h1, 384, 1536);
    k_gemm<3, 0><<<dim3(260, 3), 256, 0, stream>>>(h1, wt_ff2 + (size_t)lay * 589824,
                                                   ff_b2 + lay * 384, x, x, 1536, 384);
  }

  k_lncls<<<512, 128, 0, stream>>>(x, fin_ln_w, fin_ln_b, xcls);
  k_gemm<1, 0><<<dim3(4, 8), 256, 0, stream>>>(xcls, wt_head, hb_pad, nullptr, d_out, 384, 1000);
}

// Round 5
// 5071.222 us; speedup vs baseline: 1.1224x; 1.1224x over previous
//
#include <hip/hip_runtime.h>
#include <cstdint>
#include <cstddef>

// ---------------------------------------------------------------------------
// ViT forward, MI355X. B=512, DIM=384, HEADS=6, DH=64, DEPTH=12, MLP=1536,
// N=65 tokens, top-K=16 sparse attention with relative position bias.
// bf16 MFMA (16x16x32) for all GEMMs, fp32 residual/LN/softmax/PV weights.
// R5: attention = A (QK^T+bias -> fp32 scores, global/L3) ->
//     T (one THREAD per row: sortable-key uint top-16 cascade, ILP-2 chains,
//        bitonic top-k merge, softmax -> (w,idx) pairs, 100% lane fill) ->
//     V (PV from bank-padded LDS V).
// ---------------------------------------------------------------------------

typedef __attribute__((ext_vector_type(8))) short bf16x8;
typedef __attribute__((ext_vector_type(4))) float f32x4;
typedef __attribute__((ext_vector_type(4))) unsigned short u16x4;

__device__ __forceinline__ unsigned short f2bf(float f) {
  unsigned u = __float_as_uint(f);
  u += 0x7FFF + ((u >> 16) & 1);            // RNE
  return (unsigned short)(u >> 16);
}
__device__ __forceinline__ float bf2f(unsigned short h) {
  return __uint_as_float(((unsigned)h) << 16);
}
__device__ __forceinline__ float gelu_f(float v) {
  return 0.5f * v * (1.f + erff(v * 0.70710678118654752440f));
}

typedef const __attribute__((address_space(1))) unsigned int* gas1_t;
typedef __attribute__((address_space(3))) unsigned int* las3_t;
__device__ __forceinline__ void async16(const void* g, void* l) {
  __builtin_amdgcn_global_load_lds((gas1_t)g, (las3_t)l, 16, 0, 0);
}

// ---------------------------------------------------------------------------
// Weight convert: fp32 [mat][K][N] -> bf16 [mat][Npad][K] (transposed, padded)
// ---------------------------------------------------------------------------
__global__ void k_tconv(const float* __restrict__ in, unsigned short* __restrict__ out,
                        int K, int N, int Npad, int total) {
  int idx = blockIdx.x * 256 + threadIdx.x;
  if (idx >= total) return;
  int per = Npad * K;
  int mat = idx / per;
  int rem = idx - mat * per;
  int n = rem / K;
  int kk = rem - n * K;
  float v = 0.f;
  if (n < N) v = in[(size_t)mat * K * N + (size_t)kk * N + n];
  out[idx] = f2bf(v);
}

__global__ void k_padhb(const float* __restrict__ hb, float* __restrict__ out) {
  int i = blockIdx.x * 256 + threadIdx.x;
  if (i < 1024) out[i] = (i < 1000) ? hb[i] : 0.f;
}

// ---------------------------------------------------------------------------
// Patch extraction + LN over 768 -> bf16 rows [32768 x 768]
// ---------------------------------------------------------------------------
__global__ void k_patchln(const float* __restrict__ img,
                          const float* __restrict__ w1, const float* __restrict__ b1,
                          unsigned short* __restrict__ Xp) {
  const int p = blockIdx.x;               // b*64 + patch
  const int b = p >> 6, pl = p & 63;
  const int gr = pl >> 3, gc = pl & 7;
  const int t = threadIdx.x;              // 256
  __shared__ float buf[768];
  __shared__ float ps[4], ps2[4];
#pragma unroll
  for (int s = 0; s < 3; ++s) {
    int rr = s * 16 + (t >> 4);           // 0..47 = (c,p1)
    int c = rr >> 4, p1 = rr & 15, p2 = t & 15;
    float v = img[(((size_t)b * 3 + c) * 128 + (gr * 16 + p1)) * 128 + gc * 16 + p2];
    buf[(p1 * 16 + p2) * 3 + c] = v;
  }
  __syncthreads();
  float e0 = buf[t], e1 = buf[t + 256], e2 = buf[t + 512];
  float s = e0 + e1 + e2;
  float s2 = e0 * e0 + e1 * e1 + e2 * e2;
  for (int off = 32; off; off >>= 1) { s += __shfl_xor(s, off); s2 += __shfl_xor(s2, off); }
  if ((t & 63) == 0) { ps[t >> 6] = s; ps2[t >> 6] = s2; }
  __syncthreads();
  float S = ps[0] + ps[1] + ps[2] + ps[3];
  float S2 = ps2[0] + ps2[1] + ps2[2] + ps2[3];
  float mu = S * (1.f / 768.f);
  float rs = rsqrtf(S2 * (1.f / 768.f) - mu * mu + 1e-5f);
  size_t ob = (size_t)p * 768;
  Xp[ob + t]       = f2bf((e0 - mu) * rs * w1[t]       + b1[t]);
  Xp[ob + t + 256] = f2bf((e1 - mu) * rs * w1[t + 256] + b1[t + 256]);
  Xp[ob + t + 512] = f2bf((e2 - mu) * rs * w1[t + 512] + b1[t + 512]);
}

// ---------------------------------------------------------------------------
// LN over 384 (fp32 in) -> bf16 out. 128 threads/row.
// ---------------------------------------------------------------------------
__global__ void k_ln384(const float* __restrict__ X, const float* __restrict__ w,
                        const float* __restrict__ bb, unsigned short* __restrict__ H) {
  const int row = blockIdx.x;
  const int t = threadIdx.x;
  const float* xr = X + (size_t)row * 384;
  float e0 = xr[t], e1 = xr[t + 128], e2 = xr[t + 256];
  float s = e0 + e1 + e2, s2 = e0 * e0 + e1 * e1 + e2 * e2;
  for (int off = 32; off; off >>= 1) { s += __shfl_xor(s, off); s2 += __shfl_xor(s2, off); }
  __shared__ float ps[2], ps2[2];
  if ((t & 63) == 0) { ps[t >> 6] = s; ps2[t >> 6] = s2; }
  __syncthreads();
  float S = ps[0] + ps[1], S2 = ps2[0] + ps2[1];
  float mu = S * (1.f / 384.f);
  float rs = rsqrtf(S2 * (1.f / 384.f) - mu * mu + 1e-5f);
  size_t ob = (size_t)row * 384;
  H[ob + t]       = f2bf((e0 - mu) * rs * w[t]       + bb[t]);
  H[ob + t + 128] = f2bf((e1 - mu) * rs * w[t + 128] + bb[t + 128]);
  H[ob + t + 256] = f2bf((e2 - mu) * rs * w[t + 256] + bb[t + 256]);
}

// LN(cls row) -> bf16 [512 x 384]
__global__ void k_lncls(const float* __restrict__ X, const float* __restrict__ w,
                        const float* __restrict__ bb, unsigned short* __restrict__ H) {
  const int b = blockIdx.x;
  const int t = threadIdx.x;
  const float* xr = X + (size_t)b * 65 * 384;
  float e0 = xr[t], e1 = xr[t + 128], e2 = xr[t + 256];
  float s = e0 + e1 + e2, s2 = e0 * e0 + e1 * e1 + e2 * e2;
  for (int off = 32; off; off >>= 1) { s += __shfl_xor(s, off); s2 += __shfl_xor(s2, off); }
  __shared__ float ps[2], ps2[2];
  if ((t & 63) == 0) { ps[t >> 6] = s; ps2[t >> 6] = s2; }
  __syncthreads();
  float S = ps[0] + ps[1], S2 = ps2[0] + ps2[1];
  float mu = S * (1.f / 384.f);
  float rs = rsqrtf(S2 * (1.f / 384.f) - mu * mu + 1e-5f);
  size_t ob = (size_t)b * 384;
  H[ob + t]       = f2bf((e0 - mu) * rs * w[t]       + bb[t]);
  H[ob + t + 128] = f2bf((e1 - mu) * rs * w[t + 128] + bb[t + 128]);
  H[ob + t + 256] = f2bf((e2 - mu) * rs * w[t + 256] + bb[t + 256]);
}

// LN(patch-embed GEMM out) + pos_emb -> x fp32 rows (token 1+pl)
__global__ void k_ln2pos(const float* __restrict__ tmp, const float* __restrict__ w,
                         const float* __restrict__ bb, const float* __restrict__ pos,
                         float* __restrict__ Xout) {
  const int p = blockIdx.x;               // 0..32767
  const int b = p >> 6, pl = p & 63;
  const int t = threadIdx.x;
  const float* xr = tmp + (size_t)p * 384;
  float e0 = xr[t], e1 = xr[t + 128], e2 = xr[t + 256];
  float s = e0 + e1 + e2, s2 = e0 * e0 + e1 * e1 + e2 * e2;
  for (int off = 32; off; off >>= 1) { s += __shfl_xor(s, off); s2 += __shfl_xor(s2, off); }
  __shared__ float ps[2], ps2[2];
  if ((t & 63) == 0) { ps[t >> 6] = s; ps2[t >> 6] = s2; }
  __syncthreads();
  float S = ps[0] + ps[1], S2 = ps2[0] + ps2[1];
  float mu = S * (1.f / 384.f);
  float rs = rsqrtf(S2 * (1.f / 384.f) - mu * mu + 1e-5f);
  const float* pr = pos + (size_t)(1 + pl) * 384;
  float* orow = Xout + ((size_t)b * 65 + 1 + pl) * 384;
  orow[t]       = (e0 - mu) * rs * w[t]       + bb[t]       + pr[t];
  orow[t + 128] = (e1 - mu) * rs * w[t + 128] + bb[t + 128] + pr[t + 128];
  orow[t + 256] = (e2 - mu) * rs * w[t + 256] + bb[t + 256] + pr[t + 256];
}

__global__ void k_cls(const float* __restrict__ cls, const float* __restrict__ pos,
                      float* __restrict__ Xout) {
  int idx = blockIdx.x * 256 + threadIdx.x;
  if (idx >= 512 * 384) return;
  int b = idx / 384, d = idx - b * 384;
  Xout[(size_t)b * 65 * 384 + d] = cls[d] + pos[d];
}

// ---------------------------------------------------------------------------
// GEMM: C[M x Nreal] = A_bf16[M x K] @ Wt_bf16[Npad x K]^T (+bias)(+gelu)(+res)
// 128x128 tile, BK=64, 256 thr = 4 waves (2x2 of 64x64), mfma 16x16x32 bf16.
// EPI: 0=none 1=bias 2=bias+gelu 3=bias+residual.  OUTBF: 1 -> bf16 out.
// ---------------------------------------------------------------------------
template <int EPI, int OUTBF>
__global__ __launch_bounds__(256, 2) void k_gemm(
    const unsigned short* __restrict__ A,
    const unsigned short* __restrict__ Wt,
    const float* __restrict__ bias,
    const float* __restrict__ Res,
    void* __restrict__ Out,
    int K, int Nreal) {
  __shared__ alignas(16) unsigned short As[128 * 64];
  __shared__ alignas(16) unsigned short Bs[128 * 64];
  const int t = threadIdx.x;
  const int w = t >> 6, l = t & 63;
  const int m0 = blockIdx.x * 128, n0 = blockIdx.y * 128;
  const int wm = w & 1, wn = w >> 1;

  f32x4 acc[4][4] = {};

  const int rA = t >> 3;                   // 0..31
  const int cb = t & 7;                    // 16B chunk in row
  const unsigned short* Ag = A + (size_t)(m0 + rA) * K + cb * 8;
  const unsigned short* Bg = Wt + (size_t)(n0 + rA) * K + cb * 8;

  for (int k0 = 0; k0 < K; k0 += 64) {
#pragma unroll
    for (int p = 0; p < 4; ++p) {
      async16(Ag + (size_t)(p * 32) * K + k0, &As[p * 2048 + t * 8]);
      async16(Bg + (size_t)(p * 32) * K + k0, &Bs[p * 2048 + t * 8]);
    }
    __syncthreads();
#pragma unroll
    for (int kk = 0; kk < 64; kk += 32) {
      bf16x8 af[4], bfr[4];
      const int kof = kk + (l >> 4) * 8;
      const int rsel = l & 15;
#pragma unroll
      for (int i = 0; i < 4; ++i) {
        af[i]  = *(const bf16x8*)&As[(wm * 64 + i * 16 + rsel) * 64 + kof];
        bfr[i] = *(const bf16x8*)&Bs[(wn * 64 + i * 16 + rsel) * 64 + kof];
      }
#pragma unroll
      for (int i = 0; i < 4; ++i)
#pragma unroll
        for (int j = 0; j < 4; ++j)
          acc[i][j] = __builtin_amdgcn_mfma_f32_16x16x32_bf16(af[i], bfr[j], acc[i][j], 0, 0, 0);
    }
    __syncthreads();
  }

  const int colq = l & 15, rowq = (l >> 4) * 4;
#pragma unroll
  for (int i = 0; i < 4; ++i) {
    const int rb = m0 + wm * 64 + i * 16 + rowq;
#pragma unroll
    for (int j = 0; j < 4; ++j) {
      const int c = n0 + wn * 64 + j * 16 + colq;
      float bv = 0.f;
      if (EPI >= 1) bv = bias[c];
#pragma unroll
      for (int rg = 0; rg < 4; ++rg) {
        const int r = rb + rg;
        float v = acc[i][j][rg] + bv;
        if (EPI == 2) v = gelu_f(v);
        if (EPI == 3) v += Res[(size_t)r * Nreal + c];
        if (c < Nreal) {
          if (OUTBF) ((unsigned short*)Out)[(size_t)r * Nreal + c] = f2bf(v);
          else       ((float*)Out)[(size_t)r * Nreal + c] = v;
        }
      }
    }
  }
}

// ---------------------------------------------------------------------------
// k_attnA: per (b,h): scores[i][j] = dot(q_i,k_j)*0.125 + relpos bias,
// row-major fp32 to global [blk][65][68] (L3-resident).
// ---------------------------------------------------------------------------
__global__ __launch_bounds__(256, 4) void k_attnA(
    const unsigned short* __restrict__ qkvb,
    const float* __restrict__ btab,
    float* __restrict__ scores) {
  const int blk = blockIdx.x;
  const int b = blk / 6, h = blk - b * 6;
  __shared__ alignas(16) union UU {
    unsigned short qk[2 * 80 * 64];       // 20480 B
    float ds[65 * 68];                    // 17680 B, overlaid after mfma phase
  } u;
  __shared__ float btl[225];
  const int t = threadIdx.x;
  const size_t base = (size_t)b * 65 * 1152 + h * 64;

  if (t < 225) btl[t] = btab[t];
  for (int idx = t; idx < 520; idx += 256) {
    int r = idx >> 3, c = idx & 7;
    const unsigned short* gp = qkvb + base + (size_t)r * 1152 + c * 8;
    async16(gp, &u.qk[idx * 8]);
    async16(gp + 384, &u.qk[80 * 64 + idx * 8]);
  }
  __syncthreads();

  const int w = t >> 6, l = t & 63;
  f32x4 accs[7];
#pragma unroll
  for (int s = 0; s < 7; ++s) {
    int tt = w + s * 4;
    f32x4 a = {0.f, 0.f, 0.f, 0.f};
    if (tt < 25) {
      int it = tt / 5, jt = tt - it * 5;
#pragma unroll
      for (int kk = 0; kk < 64; kk += 32) {
        int kof = kk + (l >> 4) * 8;
        bf16x8 qa = *(const bf16x8*)&u.qk[(it * 16 + (l & 15)) * 64 + kof];
        bf16x8 kb = *(const bf16x8*)&u.qk[80 * 64 + (jt * 16 + (l & 15)) * 64 + kof];
        a = __builtin_amdgcn_mfma_f32_16x16x32_bf16(qa, kb, a, 0, 0, 0);
      }
    }
    accs[s] = a;
  }
  __syncthreads();                         // all qk reads done; overlay ds

#pragma unroll
  for (int s = 0; s < 7; ++s) {
    int tt = w + s * 4;
    if (tt < 25) {
      int it = tt / 5, jt = tt - it * 5;
      int j = jt * 16 + (l & 15);          // key (col)
      int ib = it * 16 + (l >> 4) * 4;     // query base (row)
      if (j < 65) {
#pragma unroll
        for (int rg = 0; rg < 4; ++rg) {
          int i = ib + rg;
          if (i < 65) {
            float bias = 0.f;
            if (i > 0 && j > 0) {
              int ri = (i - 1) >> 3, ci = (i - 1) & 7;
              int rj = (j - 1) >> 3, cj = (j - 1) & 7;
              bias = btl[(ri - rj + 7) * 15 + (ci - cj + 7)];
            }
            u.ds[i * 68 + j] = accs[s][rg] * 0.125f + bias;
          }
        }
      }
    }
  }
  __syncthreads();

  float* sg = scores + (size_t)blk * 4420;
  for (int idx = t; idx < 1105; idx += 256)
    *(f32x4*)(sg + idx * 4) = *(const f32x4*)&u.ds[idx * 4];
}

// ---------------------------------------------------------------------------
// k_attnT: one thread per (blk,row): top-16 of 65 scores via sortable-uint
// keys (index embedded, stable lowest-index ties == jax.lax.top_k), two
// interleaved min/max cascades (ILP), bitonic top-k merge, softmax ->
// 16 (weight, idx) pairs, 128B contiguous per thread.
// Key: ((bits ^ (sext(sign)|0x80000000)) & ~0x7F) | (127-j). Monotone in
// value; value recovered from key (<=127 ulp error, irrelevant in exp).
// ---------------------------------------------------------------------------
__device__ __forceinline__ unsigned mkkey(float v, int j) {
  unsigned bits = __float_as_uint(v);
  unsigned m = (unsigned)(((int)bits) >> 31) | 0x80000000u;
  return ((bits ^ m) & 0xFFFFFF80u) | (unsigned)(127 - j);
}
__device__ __forceinline__ float deckey(unsigned k) {
  unsigned kb = k & 0xFFFFFF80u;
  unsigned bb = (kb & 0x80000000u) ? (kb ^ 0x80000000u) : ~kb;
  return __uint_as_float(bb);
}
__device__ __forceinline__ void cas16(unsigned* lv, unsigned x) {
#pragma unroll
  for (int i = 0; i < 16; ++i) {
    unsigned lo = min(lv[i], x);
    lv[i] = max(lv[i], x);
    x = lo;
  }
}

__global__ __launch_bounds__(256) void k_attnT(
    const float* __restrict__ scores,
    float* __restrict__ pairs) {
  const int R = blockIdx.x * 256 + threadIdx.x;   // 0..199679
  const int blk = R / 65, i = R - blk * 65;
  const float* row = scores + (size_t)blk * 4420 + (size_t)i * 68;

  unsigned lvA[16], lvB[16];
#pragma unroll
  for (int s = 0; s < 16; ++s) { lvA[s] = 0u; lvB[s] = 0u; }

#pragma unroll
  for (int c = 0; c < 16; ++c) {
    f32x4 v4 = *(const f32x4*)(row + c * 4);
    int j0 = c * 4;
    unsigned k0 = mkkey(v4.x, j0);
    unsigned k1 = mkkey(v4.y, j0 + 1);
    unsigned k2 = mkkey(v4.z, j0 + 2);
    unsigned k3 = mkkey(v4.w, j0 + 3);
    cas16(lvA, k0); cas16(lvB, k1); cas16(lvA, k2); cas16(lvB, k3);
  }
  cas16(lvA, mkkey(row[64], 64));

  unsigned C[16];
#pragma unroll
  for (int s = 0; s < 16; ++s) C[s] = max(lvA[s], lvB[15 - s]);

  float m0 = deckey(max(lvA[0], lvB[0]));
  float e[16];
  float sum = 0.f;
#pragma unroll
  for (int s = 0; s < 16; ++s) { e[s] = __expf(deckey(C[s]) - m0); sum += e[s]; }
  float inv = 1.f / sum;

  float out[32];
#pragma unroll
  for (int s = 0; s < 16; ++s) {
    out[2 * s] = e[s] * inv;
    out[2 * s + 1] = __int_as_float(127 - (int)(C[s] & 0x7Fu));
  }
  float* og = pairs + (size_t)R * 32;
#pragma unroll
  for (int s = 0; s < 8; ++s)
    *(f32x4*)(og + s * 4) = *(const f32x4*)&out[s * 4];
}

// ---------------------------------------------------------------------------
// k_attnV: per (b,h): PV from bank-padded LDS V with (w,idx) pairs.
// ---------------------------------------------------------------------------
__global__ __launch_bounds__(128, 4) void k_attnV(
    const unsigned short* __restrict__ qkvb,
    const float* __restrict__ pairs,
    unsigned short* __restrict__ Obuf) {
  const int blk = blockIdx.x;
  const int b = blk / 6, h = blk - b * 6;
  __shared__ alignas(16) unsigned short vsb[65 * 72];   // 9360 B (pad 72)
  __shared__ alignas(16) float prs[65 * 32];            // 8320 B
  const int t = threadIdx.x;
  const size_t base = (size_t)b * 65 * 1152 + h * 64;
  const float* pg = pairs + (size_t)blk * 65 * 32;

  for (int idx = t; idx < 520; idx += 128) {
    int r = idx >> 3, c = idx & 7;
    bf16x8 raw = *(const bf16x8*)(qkvb + base + (size_t)r * 1152 + 768 + c * 8);
    *(bf16x8*)&vsb[r * 72 + c * 8] = raw;
    *(f32x4*)&prs[idx * 4] = *(const f32x4*)(pg + idx * 4);
  }
  __syncthreads();

  const size_t obase = (size_t)b * 65 * 384 + h * 64;
  for (int task = t; task < 65 * 16; task += 128) {
    int i = task >> 4, dc = task & 15;
    float a0 = 0.f, a1 = 0.f, a2 = 0.f, a3 = 0.f;
#pragma unroll
    for (int s = 0; s < 16; ++s) {
      float wv = prs[i * 32 + 2 * s];
      int j = __float_as_int(prs[i * 32 + 2 * s + 1]);
      u16x4 raw = *(const u16x4*)&vsb[j * 72 + dc * 4];
      a0 += wv * bf2f(raw.x);
      a1 += wv * bf2f(raw.y);
      a2 += wv * bf2f(raw.z);
      a3 += wv * bf2f(raw.w);
    }
    u16x4 o = {f2bf(a0), f2bf(a1), f2bf(a2), f2bf(a3)};
    *(u16x4*)&Obuf[obase + (size_t)i * 384 + dc * 4] = o;
  }
}

// ---------------------------------------------------------------------------
extern "C" void kernel_launch(void* const* d_in, const int* in_sizes, int n_in,
                              void* d_out, int out_size, void* d_ws, size_t ws_size,
                              hipStream_t stream) {
  (void)in_sizes; (void)n_in; (void)out_size; (void)ws_size;
  const float* img       = (const float*)d_in[0];
  const float* pe_ln1_w  = (const float*)d_in[1];
  const float* pe_ln1_b  = (const float*)d_in[2];
  const float* pe_w      = (const float*)d_in[3];
  const float* pe_b      = (const float*)d_in[4];
  const float* pe_ln2_w  = (const float*)d_in[5];
  const float* pe_ln2_b  = (const float*)d_in[6];
  const float* cls_tok   = (const float*)d_in[7];
  const float* pos_emb   = (const float*)d_in[8];
  const float* attn_ln_w = (const float*)d_in[9];
  const float* attn_ln_b = (const float*)d_in[10];
  const float* qkv_w     = (const float*)d_in[11];
  const float* out_w     = (const float*)d_in[12];
  const float* out_b     = (const float*)d_in[13];
  const float* btab      = (const float*)d_in[14];
  const float* ff_ln_w   = (const float*)d_in[15];
  const float* ff_ln_b   = (const float*)d_in[16];
  const float* ff_w1     = (const float*)d_in[17];
  const float* ff_b1     = (const float*)d_in[18];
  const float* ff_w2     = (const float*)d_in[19];
  const float* ff_b2     = (const float*)d_in[20];
  const float* fin_ln_w  = (const float*)d_in[21];
  const float* fin_ln_b  = (const float*)d_in[22];
  const float* head_w    = (const float*)d_in[23];
  const float* head_b    = (const float*)d_in[24];

  char* ws = (char*)d_ws;
  unsigned short* wt_pe   = (unsigned short*)(ws + 0);          //  384 x 768
  unsigned short* wt_qkv  = (unsigned short*)(ws + 589824);     // 12 x 1152 x 384
  unsigned short* wt_out  = (unsigned short*)(ws + 11206656);   // 12 x 384 x 384
  unsigned short* wt_ff1  = (unsigned short*)(ws + 14745600);   // 12 x 1536 x 384
  unsigned short* wt_ff2  = (unsigned short*)(ws + 28901376);   // 12 x 384 x 1536
  unsigned short* wt_head = (unsigned short*)(ws + 43057152);   // 1024 x 384
  float*          hb_pad  = (float*)(ws + 43843584);            // 1024
  float*          x       = (float*)(ws + 43847680);            // 33280 x 384 f32
  unsigned short* hbuf    = (unsigned short*)(ws + 94965760);   // 33280 x 384 bf16 (h / o)
  unsigned short* qkvb    = (unsigned short*)(ws + 120524800);  // 33280 x 1152 bf16
  unsigned short* h1      = (unsigned short*)(ws + 197201920);  // 33280 x 1536 bf16
  unsigned short* xcls    = (unsigned short*)(ws + 299438080);  // 512 x 384 bf16

  unsigned short* Xp = qkvb;          // overlay: 32768x768 bf16, pre-layer only
  float* tmp = (float*)h1;            // overlay: 32768x384 f32, pre-layer only
  float* scoresb = (float*)h1;        // overlay: 3072 x 4420 f32 (54.3 MB)
  float* pairsb  = (float*)(ws + 251514880);  // 199680 x 32 f32 (25.6 MB, in h1 region)

  // one-time (per launch) weight transpose + bf16 convert
  k_tconv<<<dim3((294912 + 255) / 256), 256, 0, stream>>>(pe_w, wt_pe, 768, 384, 384, 294912);
  k_tconv<<<dim3((5308416 + 255) / 256), 256, 0, stream>>>(qkv_w, wt_qkv, 384, 1152, 1152, 5308416);
  k_tconv<<<dim3((1769472 + 255) / 256), 256, 0, stream>>>(out_w, wt_out, 384, 384, 384, 1769472);
  k_tconv<<<dim3((7077888 + 255) / 256), 256, 0, stream>>>(ff_w1, wt_ff1, 384, 1536, 1536, 7077888);
  k_tconv<<<dim3((7077888 + 255) / 256), 256, 0, stream>>>(ff_w2, wt_ff2, 1536, 384, 384, 7077888);
  k_tconv<<<dim3((393216 + 255) / 256), 256, 0, stream>>>(head_w, wt_head, 384, 1000, 1024, 393216);
  k_padhb<<<4, 256, 0, stream>>>(head_b, hb_pad);

  // patch embed
  k_patchln<<<32768, 256, 0, stream>>>(img, pe_ln1_w, pe_ln1_b, Xp);
  k_gemm<1, 0><<<dim3(256, 3), 256, 0, stream>>>(Xp, wt_pe, pe_b, nullptr, tmp, 768, 384);
  k_ln2pos<<<32768, 128, 0, stream>>>(tmp, pe_ln2_w, pe_ln2_b, pos_emb, x);
  k_cls<<<768, 256, 0, stream>>>(cls_tok, pos_emb, x);

  for (int lay = 0; lay < 12; ++lay) {
    k_ln384<<<33280, 128, 0, stream>>>(x, attn_ln_w + lay * 384, attn_ln_b + lay * 384, hbuf);
    k_gemm<0, 1><<<dim3(260, 9), 256, 0, stream>>>(hbuf, wt_qkv + (size_t)lay * 442368,
                                                   nullptr, nullptr, qkvb, 384, 1152);
    k_attnA<<<3072, 256, 0, stream>>>(qkvb, btab + lay * 225, scoresb);
    k_attnT<<<780, 256, 0, stream>>>(scoresb, pairsb);
    k_attnV<<<3072, 128, 0, stream>>>(qkvb, pairsb, hbuf);
    k_gemm<3, 0><<<dim3(260, 3), 256, 0, stream>>>(hbuf, wt_out + (size_t)lay * 147456,
                                                   out_b + lay * 384, x, x, 384, 384);
    k_ln384<<<33280, 128, 0, stream>>>(x, ff_ln_w + lay * 384, ff_ln_b + lay * 384, hbuf);
    k_gemm<2, 1><<<dim3(260, 12), 256, 0, stream>>>(hbuf, wt_ff1 + (size_t)lay * 589824,
                                                    ff_b1 + lay * 1536, nullptr, h1, 384, 1536);
    k_gemm<3, 0><<<dim3(260, 3), 256, 0, stream>>>(h1, wt_ff2 + (size_t)lay * 589824,
                                                   ff_b2 + lay * 384, x, x, 1536, 384);
  }

  k_lncls<<<512, 128, 0, stream>>>(x, fin_ln_w, fin_ln_b, xcls);
  k_gemm<1, 0><<<dim3(4, 8), 256, 0, stream>>>(xcls, wt_head, hb_pad, nullptr, d_out, 384, 1000);
}

// Round 6
// 4913.033 us; speedup vs baseline: 1.1586x; 1.0322x over previous
//
#include <hip/hip_runtime.h>
#include <cstdint>
#include <cstddef>

// ---------------------------------------------------------------------------
// ViT forward, MI355X. B=512, DIM=384, HEADS=6, DH=64, DEPTH=12, MLP=1536,
// N=65 tokens, top-K=16 sparse attention with relative position bias.
// bf16 MFMA (16x16x32) for all GEMMs, fp32 residual/LN/softmax/PV weights.
// R6: k_gemm grid swizzled n-fastest (A-tile shared by concurrent blocks ->
//     L2/L3 hits instead of HBM refetch); occupancy bound 2 -> 3 blocks/CU.
// ---------------------------------------------------------------------------

typedef __attribute__((ext_vector_type(8))) short bf16x8;
typedef __attribute__((ext_vector_type(4))) float f32x4;
typedef __attribute__((ext_vector_type(4))) unsigned short u16x4;

__device__ __forceinline__ unsigned short f2bf(float f) {
  unsigned u = __float_as_uint(f);
  u += 0x7FFF + ((u >> 16) & 1);            // RNE
  return (unsigned short)(u >> 16);
}
__device__ __forceinline__ float bf2f(unsigned short h) {
  return __uint_as_float(((unsigned)h) << 16);
}
__device__ __forceinline__ float gelu_f(float v) {
  return 0.5f * v * (1.f + erff(v * 0.70710678118654752440f));
}

typedef const __attribute__((address_space(1))) unsigned int* gas1_t;
typedef __attribute__((address_space(3))) unsigned int* las3_t;
__device__ __forceinline__ void async16(const void* g, void* l) {
  __builtin_amdgcn_global_load_lds((gas1_t)g, (las3_t)l, 16, 0, 0);
}

// ---------------------------------------------------------------------------
// Weight convert: fp32 [mat][K][N] -> bf16 [mat][Npad][K] (transposed, padded)
// ---------------------------------------------------------------------------
__global__ void k_tconv(const float* __restrict__ in, unsigned short* __restrict__ out,
                        int K, int N, int Npad, int total) {
  int idx = blockIdx.x * 256 + threadIdx.x;
  if (idx >= total) return;
  int per = Npad * K;
  int mat = idx / per;
  int rem = idx - mat * per;
  int n = rem / K;
  int kk = rem - n * K;
  float v = 0.f;
  if (n < N) v = in[(size_t)mat * K * N + (size_t)kk * N + n];
  out[idx] = f2bf(v);
}

__global__ void k_padhb(const float* __restrict__ hb, float* __restrict__ out) {
  int i = blockIdx.x * 256 + threadIdx.x;
  if (i < 1024) out[i] = (i < 1000) ? hb[i] : 0.f;
}

// ---------------------------------------------------------------------------
// Patch extraction + LN over 768 -> bf16 rows [32768 x 768]
// ---------------------------------------------------------------------------
__global__ void k_patchln(const float* __restrict__ img,
                          const float* __restrict__ w1, const float* __restrict__ b1,
                          unsigned short* __restrict__ Xp) {
  const int p = blockIdx.x;               // b*64 + patch
  const int b = p >> 6, pl = p & 63;
  const int gr = pl >> 3, gc = pl & 7;
  const int t = threadIdx.x;              // 256
  __shared__ float buf[768];
  __shared__ float ps[4], ps2[4];
#pragma unroll
  for (int s = 0; s < 3; ++s) {
    int rr = s * 16 + (t >> 4);           // 0..47 = (c,p1)
    int c = rr >> 4, p1 = rr & 15, p2 = t & 15;
    float v = img[(((size_t)b * 3 + c) * 128 + (gr * 16 + p1)) * 128 + gc * 16 + p2];
    buf[(p1 * 16 + p2) * 3 + c] = v;
  }
  __syncthreads();
  float e0 = buf[t], e1 = buf[t + 256], e2 = buf[t + 512];
  float s = e0 + e1 + e2;
  float s2 = e0 * e0 + e1 * e1 + e2 * e2;
  for (int off = 32; off; off >>= 1) { s += __shfl_xor(s, off); s2 += __shfl_xor(s2, off); }
  if ((t & 63) == 0) { ps[t >> 6] = s; ps2[t >> 6] = s2; }
  __syncthreads();
  float S = ps[0] + ps[1] + ps[2] + ps[3];
  float S2 = ps2[0] + ps2[1] + ps2[2] + ps2[3];
  float mu = S * (1.f / 768.f);
  float rs = rsqrtf(S2 * (1.f / 768.f) - mu * mu + 1e-5f);
  size_t ob = (size_t)p * 768;
  Xp[ob + t]       = f2bf((e0 - mu) * rs * w1[t]       + b1[t]);
  Xp[ob + t + 256] = f2bf((e1 - mu) * rs * w1[t + 256] + b1[t + 256]);
  Xp[ob + t + 512] = f2bf((e2 - mu) * rs * w1[t + 512] + b1[t + 512]);
}

// ---------------------------------------------------------------------------
// LN over 384 (fp32 in) -> bf16 out. 128 threads/row.
// ---------------------------------------------------------------------------
__global__ void k_ln384(const float* __restrict__ X, const float* __restrict__ w,
                        const float* __restrict__ bb, unsigned short* __restrict__ H) {
  const int row = blockIdx.x;
  const int t = threadIdx.x;
  const float* xr = X + (size_t)row * 384;
  float e0 = xr[t], e1 = xr[t + 128], e2 = xr[t + 256];
  float s = e0 + e1 + e2, s2 = e0 * e0 + e1 * e1 + e2 * e2;
  for (int off = 32; off; off >>= 1) { s += __shfl_xor(s, off); s2 += __shfl_xor(s2, off); }
  __shared__ float ps[2], ps2[2];
  if ((t & 63) == 0) { ps[t >> 6] = s; ps2[t >> 6] = s2; }
  __syncthreads();
  float S = ps[0] + ps[1], S2 = ps2[0] + ps2[1];
  float mu = S * (1.f / 384.f);
  float rs = rsqrtf(S2 * (1.f / 384.f) - mu * mu + 1e-5f);
  size_t ob = (size_t)row * 384;
  H[ob + t]       = f2bf((e0 - mu) * rs * w[t]       + bb[t]);
  H[ob + t + 128] = f2bf((e1 - mu) * rs * w[t + 128] + bb[t + 128]);
  H[ob + t + 256] = f2bf((e2 - mu) * rs * w[t + 256] + bb[t + 256]);
}

// LN(cls row) -> bf16 [512 x 384]
__global__ void k_lncls(const float* __restrict__ X, const float* __restrict__ w,
                        const float* __restrict__ bb, unsigned short* __restrict__ H) {
  const int b = blockIdx.x;
  const int t = threadIdx.x;
  const float* xr = X + (size_t)b * 65 * 384;
  float e0 = xr[t], e1 = xr[t + 128], e2 = xr[t + 256];
  float s = e0 + e1 + e2, s2 = e0 * e0 + e1 * e1 + e2 * e2;
  for (int off = 32; off; off >>= 1) { s += __shfl_xor(s, off); s2 += __shfl_xor(s2, off); }
  __shared__ float ps[2], ps2[2];
  if ((t & 63) == 0) { ps[t >> 6] = s; ps2[t >> 6] = s2; }
  __syncthreads();
  float S = ps[0] + ps[1], S2 = ps2[0] + ps2[1];
  float mu = S * (1.f / 384.f);
  float rs = rsqrtf(S2 * (1.f / 384.f) - mu * mu + 1e-5f);
  size_t ob = (size_t)b * 384;
  H[ob + t]       = f2bf((e0 - mu) * rs * w[t]       + bb[t]);
  H[ob + t + 128] = f2bf((e1 - mu) * rs * w[t + 128] + bb[t + 128]);
  H[ob + t + 256] = f2bf((e2 - mu) * rs * w[t + 256] + bb[t + 256]);
}

// LN(patch-embed GEMM out) + pos_emb -> x fp32 rows (token 1+pl)
__global__ void k_ln2pos(const float* __restrict__ tmp, const float* __restrict__ w,
                         const float* __restrict__ bb, const float* __restrict__ pos,
                         float* __restrict__ Xout) {
  const int p = blockIdx.x;               // 0..32767
  const int b = p >> 6, pl = p & 63;
  const int t = threadIdx.x;
  const float* xr = tmp + (size_t)p * 384;
  float e0 = xr[t], e1 = xr[t + 128], e2 = xr[t + 256];
  float s = e0 + e1 + e2, s2 = e0 * e0 + e1 * e1 + e2 * e2;
  for (int off = 32; off; off >>= 1) { s += __shfl_xor(s, off); s2 += __shfl_xor(s2, off); }
  __shared__ float ps[2], ps2[2];
  if ((t & 63) == 0) { ps[t >> 6] = s; ps2[t >> 6] = s2; }
  __syncthreads();
  float S = ps[0] + ps[1], S2 = ps2[0] + ps2[1];
  float mu = S * (1.f / 384.f);
  float rs = rsqrtf(S2 * (1.f / 384.f) - mu * mu + 1e-5f);
  const float* pr = pos + (size_t)(1 + pl) * 384;
  float* orow = Xout + ((size_t)b * 65 + 1 + pl) * 384;
  orow[t]       = (e0 - mu) * rs * w[t]       + bb[t]       + pr[t];
  orow[t + 128] = (e1 - mu) * rs * w[t + 128] + bb[t + 128] + pr[t + 128];
  orow[t + 256] = (e2 - mu) * rs * w[t + 256] + bb[t + 256] + pr[t + 256];
}

__global__ void k_cls(const float* __restrict__ cls, const float* __restrict__ pos,
                      float* __restrict__ Xout) {
  int idx = blockIdx.x * 256 + threadIdx.x;
  if (idx >= 512 * 384) return;
  int b = idx / 384, d = idx - b * 384;
  Xout[(size_t)b * 65 * 384 + d] = cls[d] + pos[d];
}

// ---------------------------------------------------------------------------
// GEMM: C[M x Nreal] = A_bf16[M x K] @ Wt_bf16[Npad x K]^T (+bias)(+gelu)(+res)
// 128x128 tile, BK=64, 256 thr = 4 waves (2x2 of 64x64), mfma 16x16x32 bf16.
// Grid: blockIdx.x = n-tile (FASTEST -> blocks sharing an A-tile dispatch
// together and hit L2/L3), blockIdx.y = m-tile.
// EPI: 0=none 1=bias 2=bias+gelu 3=bias+residual.  OUTBF: 1 -> bf16 out.
// ---------------------------------------------------------------------------
template <int EPI, int OUTBF>
__global__ __launch_bounds__(256, 3) void k_gemm(
    const unsigned short* __restrict__ A,
    const unsigned short* __restrict__ Wt,
    const float* __restrict__ bias,
    const float* __restrict__ Res,
    void* __restrict__ Out,
    int K, int Nreal) {
  __shared__ alignas(16) unsigned short As[128 * 64];
  __shared__ alignas(16) unsigned short Bs[128 * 64];
  const int t = threadIdx.x;
  const int w = t >> 6, l = t & 63;
  const int m0 = blockIdx.y * 128, n0 = blockIdx.x * 128;
  const int wm = w & 1, wn = w >> 1;

  f32x4 acc[4][4] = {};

  const int rA = t >> 3;                   // 0..31
  const int cb = t & 7;                    // 16B chunk in row
  const unsigned short* Ag = A + (size_t)(m0 + rA) * K + cb * 8;
  const unsigned short* Bg = Wt + (size_t)(n0 + rA) * K + cb * 8;

  for (int k0 = 0; k0 < K; k0 += 64) {
#pragma unroll
    for (int p = 0; p < 4; ++p) {
      async16(Ag + (size_t)(p * 32) * K + k0, &As[p * 2048 + t * 8]);
      async16(Bg + (size_t)(p * 32) * K + k0, &Bs[p * 2048 + t * 8]);
    }
    __syncthreads();
#pragma unroll
    for (int kk = 0; kk < 64; kk += 32) {
      bf16x8 af[4], bfr[4];
      const int kof = kk + (l >> 4) * 8;
      const int rsel = l & 15;
#pragma unroll
      for (int i = 0; i < 4; ++i) {
        af[i]  = *(const bf16x8*)&As[(wm * 64 + i * 16 + rsel) * 64 + kof];
        bfr[i] = *(const bf16x8*)&Bs[(wn * 64 + i * 16 + rsel) * 64 + kof];
      }
#pragma unroll
      for (int i = 0; i < 4; ++i)
#pragma unroll
        for (int j = 0; j < 4; ++j)
          acc[i][j] = __builtin_amdgcn_mfma_f32_16x16x32_bf16(af[i], bfr[j], acc[i][j], 0, 0, 0);
    }
    __syncthreads();
  }

  const int colq = l & 15, rowq = (l >> 4) * 4;
#pragma unroll
  for (int i = 0; i < 4; ++i) {
    const int rb = m0 + wm * 64 + i * 16 + rowq;
#pragma unroll
    for (int j = 0; j < 4; ++j) {
      const int c = n0 + wn * 64 + j * 16 + colq;
      float bv = 0.f;
      if (EPI >= 1) bv = bias[c];
#pragma unroll
      for (int rg = 0; rg < 4; ++rg) {
        const int r = rb + rg;
        float v = acc[i][j][rg] + bv;
        if (EPI == 2) v = gelu_f(v);
        if (EPI == 3) v += Res[(size_t)r * Nreal + c];
        if (c < Nreal) {
          if (OUTBF) ((unsigned short*)Out)[(size_t)r * Nreal + c] = f2bf(v);
          else       ((float*)Out)[(size_t)r * Nreal + c] = v;
        }
      }
    }
  }
}

// ---------------------------------------------------------------------------
// k_attnA: per (b,h): scores[i][j] = dot(q_i,k_j)*0.125 + relpos bias,
// row-major fp32 to global [blk][65][68] (L3-resident).
// ---------------------------------------------------------------------------
__global__ __launch_bounds__(256, 4) void k_attnA(
    const unsigned short* __restrict__ qkvb,
    const float* __restrict__ btab,
    float* __restrict__ scores) {
  const int blk = blockIdx.x;
  const int b = blk / 6, h = blk - b * 6;
  __shared__ alignas(16) union UU {
    unsigned short qk[2 * 80 * 64];       // 20480 B
    float ds[65 * 68];                    // 17680 B, overlaid after mfma phase
  } u;
  __shared__ float btl[225];
  const int t = threadIdx.x;
  const size_t base = (size_t)b * 65 * 1152 + h * 64;

  if (t < 225) btl[t] = btab[t];
  for (int idx = t; idx < 520; idx += 256) {
    int r = idx >> 3, c = idx & 7;
    const unsigned short* gp = qkvb + base + (size_t)r * 1152 + c * 8;
    async16(gp, &u.qk[idx * 8]);
    async16(gp + 384, &u.qk[80 * 64 + idx * 8]);
  }
  __syncthreads();

  const int w = t >> 6, l = t & 63;
  f32x4 accs[7];
#pragma unroll
  for (int s = 0; s < 7; ++s) {
    int tt = w + s * 4;
    f32x4 a = {0.f, 0.f, 0.f, 0.f};
    if (tt < 25) {
      int it = tt / 5, jt = tt - it * 5;
#pragma unroll
      for (int kk = 0; kk < 64; kk += 32) {
        int kof = kk + (l >> 4) * 8;
        bf16x8 qa = *(const bf16x8*)&u.qk[(it * 16 + (l & 15)) * 64 + kof];
        bf16x8 kb = *(const bf16x8*)&u.qk[80 * 64 + (jt * 16 + (l & 15)) * 64 + kof];
        a = __builtin_amdgcn_mfma_f32_16x16x32_bf16(qa, kb, a, 0, 0, 0);
      }
    }
    accs[s] = a;
  }
  __syncthreads();                         // all qk reads done; overlay ds

#pragma unroll
  for (int s = 0; s < 7; ++s) {
    int tt = w + s * 4;
    if (tt < 25) {
      int it = tt / 5, jt = tt - it * 5;
      int j = jt * 16 + (l & 15);          // key (col)
      int ib = it * 16 + (l >> 4) * 4;     // query base (row)
      if (j < 65) {
#pragma unroll
        for (int rg = 0; rg < 4; ++rg) {
          int i = ib + rg;
          if (i < 65) {
            float bias = 0.f;
            if (i > 0 && j > 0) {
              int ri = (i - 1) >> 3, ci = (i - 1) & 7;
              int rj = (j - 1) >> 3, cj = (j - 1) & 7;
              bias = btl[(ri - rj + 7) * 15 + (ci - cj + 7)];
            }
            u.ds[i * 68 + j] = accs[s][rg] * 0.125f + bias;
          }
        }
      }
    }
  }
  __syncthreads();

  float* sg = scores + (size_t)blk * 4420;
  for (int idx = t; idx < 1105; idx += 256)
    *(f32x4*)(sg + idx * 4) = *(const f32x4*)&u.ds[idx * 4];
}

// ---------------------------------------------------------------------------
// k_attnT: one thread per (blk,row): top-16 of 65 scores via sortable-uint
// keys (index embedded, stable lowest-index ties == jax.lax.top_k), two
// interleaved min/max cascades (ILP), bitonic top-k merge, softmax ->
// 16 (weight, idx) pairs, 128B contiguous per thread.
// ---------------------------------------------------------------------------
__device__ __forceinline__ unsigned mkkey(float v, int j) {
  unsigned bits = __float_as_uint(v);
  unsigned m = (unsigned)(((int)bits) >> 31) | 0x80000000u;
  return ((bits ^ m) & 0xFFFFFF80u) | (unsigned)(127 - j);
}
__device__ __forceinline__ float deckey(unsigned k) {
  unsigned kb = k & 0xFFFFFF80u;
  unsigned bb = (kb & 0x80000000u) ? (kb ^ 0x80000000u) : ~kb;
  return __uint_as_float(bb);
}
__device__ __forceinline__ void cas16(unsigned* lv, unsigned x) {
#pragma unroll
  for (int i = 0; i < 16; ++i) {
    unsigned lo = min(lv[i], x);
    lv[i] = max(lv[i], x);
    x = lo;
  }
}

__global__ __launch_bounds__(256) void k_attnT(
    const float* __restrict__ scores,
    float* __restrict__ pairs) {
  const int R = blockIdx.x * 256 + threadIdx.x;   // 0..199679
  const int blk = R / 65, i = R - blk * 65;
  const float* row = scores + (size_t)blk * 4420 + (size_t)i * 68;

  unsigned lvA[16], lvB[16];
#pragma unroll
  for (int s = 0; s < 16; ++s) { lvA[s] = 0u; lvB[s] = 0u; }

#pragma unroll
  for (int c = 0; c < 16; ++c) {
    f32x4 v4 = *(const f32x4*)(row + c * 4);
    int j0 = c * 4;
    unsigned k0 = mkkey(v4.x, j0);
    unsigned k1 = mkkey(v4.y, j0 + 1);
    unsigned k2 = mkkey(v4.z, j0 + 2);
    unsigned k3 = mkkey(v4.w, j0 + 3);
    cas16(lvA, k0); cas16(lvB, k1); cas16(lvA, k2); cas16(lvB, k3);
  }
  cas16(lvA, mkkey(row[64], 64));

  unsigned C[16];
#pragma unroll
  for (int s = 0; s < 16; ++s) C[s] = max(lvA[s], lvB[15 - s]);

  float m0 = deckey(max(lvA[0], lvB[0]));
  float e[16];
  float sum = 0.f;
#pragma unroll
  for (int s = 0; s < 16; ++s) { e[s] = __expf(deckey(C[s]) - m0); sum += e[s]; }
  float inv = 1.f / sum;

  float out[32];
#pragma unroll
  for (int s = 0; s < 16; ++s) {
    out[2 * s] = e[s] * inv;
    out[2 * s + 1] = __int_as_float(127 - (int)(C[s] & 0x7Fu));
  }
  float* og = pairs + (size_t)R * 32;
#pragma unroll
  for (int s = 0; s < 8; ++s)
    *(f32x4*)(og + s * 4) = *(const f32x4*)&out[s * 4];
}

// ---------------------------------------------------------------------------
// k_attnV: per (b,h): PV from bank-padded LDS V with (w,idx) pairs.
// ---------------------------------------------------------------------------
__global__ __launch_bounds__(128, 4) void k_attnV(
    const unsigned short* __restrict__ qkvb,
    const float* __restrict__ pairs,
    unsigned short* __restrict__ Obuf) {
  const int blk = blockIdx.x;
  const int b = blk / 6, h = blk - b * 6;
  __shared__ alignas(16) unsigned short vsb[65 * 72];   // 9360 B (pad 72)
  __shared__ alignas(16) float prs[65 * 32];            // 8320 B
  const int t = threadIdx.x;
  const size_t base = (size_t)b * 65 * 1152 + h * 64;
  const float* pg = pairs + (size_t)blk * 65 * 32;

  for (int idx = t; idx < 520; idx += 128) {
    int r = idx >> 3, c = idx & 7;
    bf16x8 raw = *(const bf16x8*)(qkvb + base + (size_t)r * 1152 + 768 + c * 8);
    *(bf16x8*)&vsb[r * 72 + c * 8] = raw;
    *(f32x4*)&prs[idx * 4] = *(const f32x4*)(pg + idx * 4);
  }
  __syncthreads();

  const size_t obase = (size_t)b * 65 * 384 + h * 64;
  for (int task = t; task < 65 * 16; task += 128) {
    int i = task >> 4, dc = task & 15;
    float a0 = 0.f, a1 = 0.f, a2 = 0.f, a3 = 0.f;
#pragma unroll
    for (int s = 0; s < 16; ++s) {
      float wv = prs[i * 32 + 2 * s];
      int j = __float_as_int(prs[i * 32 + 2 * s + 1]);
      u16x4 raw = *(const u16x4*)&vsb[j * 72 + dc * 4];
      a0 += wv * bf2f(raw.x);
      a1 += wv * bf2f(raw.y);
      a2 += wv * bf2f(raw.z);
      a3 += wv * bf2f(raw.w);
    }
    u16x4 o = {f2bf(a0), f2bf(a1), f2bf(a2), f2bf(a3)};
    *(u16x4*)&Obuf[obase + (size_t)i * 384 + dc * 4] = o;
  }
}

// ---------------------------------------------------------------------------
extern "C" void kernel_launch(void* const* d_in, const int* in_sizes, int n_in,
                              void* d_out, int out_size, void* d_ws, size_t ws_size,
                              hipStream_t stream) {
  (void)in_sizes; (void)n_in; (void)out_size; (void)ws_size;
  const float* img       = (const float*)d_in[0];
  const float* pe_ln1_w  = (const float*)d_in[1];
  const float* pe_ln1_b  = (const float*)d_in[2];
  const float* pe_w      = (const float*)d_in[3];
  const float* pe_b      = (const float*)d_in[4];
  const float* pe_ln2_w  = (const float*)d_in[5];
  const float* pe_ln2_b  = (const float*)d_in[6];
  const float* cls_tok   = (const float*)d_in[7];
  const float* pos_emb   = (const float*)d_in[8];
  const float* attn_ln_w = (const float*)d_in[9];
  const float* attn_ln_b = (const float*)d_in[10];
  const float* qkv_w     = (const float*)d_in[11];
  const float* out_w     = (const float*)d_in[12];
  const float* out_b     = (const float*)d_in[13];
  const float* btab      = (const float*)d_in[14];
  const float* ff_ln_w   = (const float*)d_in[15];
  const float* ff_ln_b   = (const float*)d_in[16];
  const float* ff_w1     = (const float*)d_in[17];
  const float* ff_b1     = (const float*)d_in[18];
  const float* ff_w2     = (const float*)d_in[19];
  const float* ff_b2     = (const float*)d_in[20];
  const float* fin_ln_w  = (const float*)d_in[21];
  const float* fin_ln_b  = (const float*)d_in[22];
  const float* head_w    = (const float*)d_in[23];
  const float* head_b    = (const float*)d_in[24];

  char* ws = (char*)d_ws;
  unsigned short* wt_pe   = (unsigned short*)(ws + 0);          //  384 x 768
  unsigned short* wt_qkv  = (unsigned short*)(ws + 589824);     // 12 x 1152 x 384
  unsigned short* wt_out  = (unsigned short*)(ws + 11206656);   // 12 x 384 x 384
  unsigned short* wt_ff1  = (unsigned short*)(ws + 14745600);   // 12 x 1536 x 384
  unsigned short* wt_ff2  = (unsigned short*)(ws + 28901376);   // 12 x 384 x 1536
  unsigned short* wt_head = (unsigned short*)(ws + 43057152);   // 1024 x 384
  float*          hb_pad  = (float*)(ws + 43843584);            // 1024
  float*          x       = (float*)(ws + 43847680);            // 33280 x 384 f32
  unsigned short* hbuf    = (unsigned short*)(ws + 94965760);   // 33280 x 384 bf16 (h / o)
  unsigned short* qkvb    = (unsigned short*)(ws + 120524800);  // 33280 x 1152 bf16
  unsigned short* h1      = (unsigned short*)(ws + 197201920);  // 33280 x 1536 bf16
  unsigned short* xcls    = (unsigned short*)(ws + 299438080);  // 512 x 384 bf16

  unsigned short* Xp = qkvb;          // overlay: 32768x768 bf16, pre-layer only
  float* tmp = (float*)h1;            // overlay: 32768x384 f32, pre-layer only
  float* scoresb = (float*)h1;        // overlay: 3072 x 4420 f32 (54.3 MB)
  float* pairsb  = (float*)(ws + 251514880);  // 199680 x 32 f32 (25.6 MB, in h1 region)

  // one-time (per launch) weight transpose + bf16 convert
  k_tconv<<<dim3((294912 + 255) / 256), 256, 0, stream>>>(pe_w, wt_pe, 768, 384, 384, 294912);
  k_tconv<<<dim3((5308416 + 255) / 256), 256, 0, stream>>>(qkv_w, wt_qkv, 384, 1152, 1152, 5308416);
  k_tconv<<<dim3((1769472 + 255) / 256), 256, 0, stream>>>(out_w, wt_out, 384, 384, 384, 1769472);
  k_tconv<<<dim3((7077888 + 255) / 256), 256, 0, stream>>>(ff_w1, wt_ff1, 384, 1536, 1536, 7077888);
  k_tconv<<<dim3((7077888 + 255) / 256), 256, 0, stream>>>(ff_w2, wt_ff2, 1536, 384, 384, 7077888);
  k_tconv<<<dim3((393216 + 255) / 256), 256, 0, stream>>>(head_w, wt_head, 384, 1000, 1024, 393216);
  k_padhb<<<4, 256, 0, stream>>>(head_b, hb_pad);

  // patch embed
  k_patchln<<<32768, 256, 0, stream>>>(img, pe_ln1_w, pe_ln1_b, Xp);
  k_gemm<1, 0><<<dim3(3, 256), 256, 0, stream>>>(Xp, wt_pe, pe_b, nullptr, tmp, 768, 384);
  k_ln2pos<<<32768, 128, 0, stream>>>(tmp, pe_ln2_w, pe_ln2_b, pos_emb, x);
  k_cls<<<768, 256, 0, stream>>>(cls_tok, pos_emb, x);

  for (int lay = 0; lay < 12; ++lay) {
    k_ln384<<<33280, 128, 0, stream>>>(x, attn_ln_w + lay * 384, attn_ln_b + lay * 384, hbuf);
    k_gemm<0, 1><<<dim3(9, 260), 256, 0, stream>>>(hbuf, wt_qkv + (size_t)lay * 442368,
                                                   nullptr, nullptr, qkvb, 384, 1152);
    k_attnA<<<3072, 256, 0, stream>>>(qkvb, btab + lay * 225, scoresb);
    k_attnT<<<780, 256, 0, stream>>>(scoresb, pairsb);
    k_attnV<<<3072, 128, 0, stream>>>(qkvb, pairsb, hbuf);
    k_gemm<3, 0><<<dim3(3, 260), 256, 0, stream>>>(hbuf, wt_out + (size_t)lay * 147456,
                                                   out_b + lay * 384, x, x, 384, 384);
    k_ln384<<<33280, 128, 0, stream>>>(x, ff_ln_w + lay * 384, ff_ln_b + lay * 384, hbuf);
    k_gemm<2, 1><<<dim3(12, 260), 256, 0, stream>>>(hbuf, wt_ff1 + (size_t)lay * 589824,
                                                    ff_b1 + lay * 1536, nullptr, h1, 384, 1536);
    k_gemm<3, 0><<<dim3(3, 260), 256, 0, stream>>>(h1, wt_ff2 + (size_t)lay * 589824,
                                                   ff_b2 + lay * 384, x, x, 1536, 384);
  }

  k_lncls<<<512, 128, 0, stream>>>(x, fin_ln_w, fin_ln_b, xcls);
  k_gemm<1, 0><<<dim3(8, 4), 256, 0, stream>>>(xcls, wt_head, hb_pad, nullptr, d_out, 384, 1000);
}